// Round 2
// baseline (264.434 us; speedup 1.0000x reference)
//
#include <hip/hip_runtime.h>

// LoG: GaussianBlur(3x3, sigma=1, REFLECT_101) -> Laplacian(9x9) -> +1 -> clip[0,255]
// x: [32,512,512,3] f32 NHWC.
//
// Laplacian = outer(S9,D9)+outer(D9,S9) -> t1=vert(S9,blur), t2=vert(D9,blur),
// out = horz(D9,t1)+horz(S9,t2)+1. Reflect-101 applied at EACH stage (two-stage
// double-reflect), reproduced exactly via inline absolute-row/col reflect math.
//
// R2 changes vs R1: tile 32x16 + padded stride (LDS 50.7->29.6 KB => 5 blocks/CU),
// blur computed directly from global (3x3, L1-resident) killing the hblur phase.

#define TH 16
#define TW 32
#define FW (TW*3)        // 96 output floats per tile row
#define BP (TW+8)        // 40 blur pixels wide (±4 halo)
#define BFU (BP*3)       // 120 used floats per row
#define BF 132           // padded row stride (33 quads; odd quad-bank shift/row)
#define BHR (TH+8)       // 24 blur rows
#define HIMG 512
#define WIMG 512
#define ROWF (WIMG*3)    // 1536 floats per image row

__device__ __forceinline__ int reflect101(int i, int n) {
    i = (i < 0) ? -i : i;
    return (i >= n) ? (2 * n - 2 - i) : i;
}

__device__ __forceinline__ float4 fma4(float s, const float4& a, const float4& b) {
    return make_float4(fmaf(s, a.x, b.x), fmaf(s, a.y, b.y),
                       fmaf(s, a.z, b.z), fmaf(s, a.w, b.w));
}

__global__ __launch_bounds__(256, 5)
void log_fused(const float* __restrict__ x, float* __restrict__ out) {
    __shared__ __align__(16) float blur[BHR * BF];   // 3168 floats
    __shared__ __align__(16) float t1[TH * BF];      // 2112
    __shared__ __align__(16) float t2[TH * BF];      // 2112  => 29568 B total

    const int tid  = threadIdx.x;
    const int col0 = blockIdx.x * TW;
    const int row0 = blockIdx.y * TH;
    const float* const xn = x + (size_t)blockIdx.z * HIMG * ROWF;

    const float G0 = 0.2740686190f, G1 = 0.4518627620f;

    // ---- phase 1: blur = 3x3 Gaussian with double-reflect, global(L1) -> LDS ----
    // column-stationary: 240 threads own (float-col lc, row-parity rg); 12 rows each.
    if (tid < 240) {
        const int lc = tid % BFU;
        const int rg = tid / BFU;            // 0 or 1
        const int p  = lc / 3;
        const int ch = lc - 3 * p;
        const int gc = reflect101(col0 - 4 + p, WIMG);   // stage-2 col reflect
        const int xm = reflect101(gc - 1, WIMG) * 3 + ch; // stage-1 col reflect
        const int x0 = gc * 3 + ch;
        const int xp = reflect101(gc + 1, WIMG) * 3 + ch;
        #pragma unroll
        for (int r = rg; r < BHR; r += 2) {
            const int g  = row0 - 4 + r;
            const int gr = reflect101(g, HIMG);          // stage-2 row reflect
            const float* pa = xn + (size_t)reflect101(gr - 1, HIMG) * ROWF;
            const float* pb = xn + (size_t)gr * ROWF;
            const float* pc = xn + (size_t)reflect101(gr + 1, HIMG) * ROWF;
            const float h0 = G0 * (pa[xm] + pa[xp]) + G1 * pa[x0];
            const float h1 = G0 * (pb[xm] + pb[xp]) + G1 * pb[x0];
            const float h2 = G0 * (pc[xm] + pc[xp]) + G1 * pc[x0];
            blur[r * BF + lc] = G0 * (h0 + h2) + G1 * h1;
        }
    }
    __syncthreads();

    const float S9[9] = {1.f, 8.f, 28.f, 56.f, 70.f, 56.f, 28.f, 8.f, 1.f};
    const float D9[9] = {1.f, 4.f, 4.f, -4.f, -10.f, -4.f, 4.f, 4.f, 1.f};

    // ---- phase 2: vertical 9-tap S and D, blur -> t1,t2 (2-row register block) ----
    // 240 threads: (row-pair rg 0..7) x (quad qc 0..29), one group each.
    if (tid < 240) {
        const int rg  = tid / 30;
        const int qc  = tid - rg * 30;
        const int lr0 = rg * 2;
        const int lc  = qc * 4;
        float4 w[10];
        #pragma unroll
        for (int k = 0; k < 10; ++k)
            w[k] = *(const float4*)&blur[(lr0 + k) * BF + lc];
        float4 a1r0 = make_float4(0.f, 0.f, 0.f, 0.f), a2r0 = a1r0;
        float4 a1r1 = a1r0, a2r1 = a1r0;
        #pragma unroll
        for (int k = 0; k < 9; ++k) {
            a1r0 = fma4(S9[k], w[k],     a1r0);
            a2r0 = fma4(D9[k], w[k],     a2r0);
            a1r1 = fma4(S9[k], w[k + 1], a1r1);
            a2r1 = fma4(D9[k], w[k + 1], a2r1);
        }
        *(float4*)&t1[(lr0    ) * BF + lc] = a1r0;
        *(float4*)&t1[(lr0 + 1) * BF + lc] = a1r1;
        *(float4*)&t2[(lr0    ) * BF + lc] = a2r0;
        *(float4*)&t2[(lr0 + 1) * BF + lc] = a2r1;
    }
    __syncthreads();

    // ---- phase 3: horizontal 9-tap D(t1)+S(t2), +1, clip, float4 stores ----
    // 192 threads: (row lr 0..15) x (oct qp 0..11), 8 outputs each.
    if (tid < 192) {
        const int lr = tid / 12;
        const int qp = tid - lr * 12;
        const int lc = qp * 8;
        float w1[32], w2[32];
        #pragma unroll
        for (int q = 0; q < 8; ++q) {
            float4 v = *(const float4*)&t1[lr * BF + lc + 4 * q];
            w1[4*q+0] = v.x; w1[4*q+1] = v.y; w1[4*q+2] = v.z; w1[4*q+3] = v.w;
            float4 u = *(const float4*)&t2[lr * BF + lc + 4 * q];
            w2[4*q+0] = u.x; w2[4*q+1] = u.y; w2[4*q+2] = u.z; w2[4*q+3] = u.w;
        }
        float o[8];
        #pragma unroll
        for (int j = 0; j < 8; ++j) {
            float a = 1.0f;   // delta = 1
            #pragma unroll
            for (int k = 0; k < 9; ++k) {
                a = fmaf(D9[k], w1[j + 3 * k], a);  // taps at +3k floats (same channel)
                a = fmaf(S9[k], w2[j + 3 * k], a);
            }
            o[j] = fminf(fmaxf(a, 0.0f), 255.0f);
        }
        float* op = out + (size_t)blockIdx.z * HIMG * ROWF
                        + (size_t)(row0 + lr) * ROWF + (size_t)(col0 * 3 + lc);
        *(float4*)&op[0] = make_float4(o[0], o[1], o[2], o[3]);
        *(float4*)&op[4] = make_float4(o[4], o[5], o[6], o[7]);
    }
}

extern "C" void kernel_launch(void* const* d_in, const int* in_sizes, int n_in,
                              void* d_out, int out_size, void* d_ws, size_t ws_size,
                              hipStream_t stream) {
    const float* x = (const float*)d_in[0];
    float* outp = (float*)d_out;
    const int nimg = in_sizes[0] / (HIMG * WIMG * 3);
    dim3 grid(WIMG / TW, HIMG / TH, nimg);
    log_fused<<<grid, dim3(256, 1, 1), 0, stream>>>(x, outp);
}